// Round 4
// baseline (637.918 us; speedup 1.0000x reference)
//
#include <hip/hip_runtime.h>
#include <math.h>

#define B_   2
#define N_   10000
#define E_   160000
#define HID_ 128
#define ED_  32
#define NH_  8
#define HD_  16
#define ROWS_ (B_ * N_)   // 20000

// ---------------- CSR build ----------------

__global__ void zero_kernel(int* __restrict__ deg, int* __restrict__ cursor, int n) {
    int i = blockIdx.x * 256 + threadIdx.x;
    if (i < n) { deg[i] = 0; cursor[i] = 0; }
}

__global__ void hist_kernel(const int* __restrict__ ei, int* __restrict__ deg, int E) {
    int e = blockIdx.x * 256 + threadIdx.x;
    if (e < E) atomicAdd(&deg[ei[2 * e + 1]], 1);
}

__global__ __launch_bounds__(256) void scan_kernel(const int* __restrict__ deg,
                                                   int* __restrict__ off, int N) {
    __shared__ int sums[256];
    int t = threadIdx.x;
    int chunk = (N + 255) / 256;
    int s0 = t * chunk, s1 = min(N, s0 + chunk);
    int s = 0;
    for (int i = s0; i < s1; ++i) s += deg[i];
    sums[t] = s;
    __syncthreads();
    if (t == 0) {
        int run = 0;
        for (int i = 0; i < 256; ++i) { int v = sums[i]; sums[i] = run; run += v; }
        off[N] = run;
    }
    __syncthreads();
    int run = sums[t];
    for (int i = s0; i < s1; ++i) { off[i] = run; run += deg[i]; }
}

__global__ void fill_kernel(const int* __restrict__ ei, const int* __restrict__ off,
                            int* __restrict__ cursor, int* __restrict__ csr, int E) {
    int e = blockIdx.x * 256 + threadIdx.x;
    if (e < E) {
        int d = ei[2 * e + 1];
        int p = atomicAdd(&cursor[d], 1);
        csr[off[d] + p] = e;
    }
}

// ---------------- node QKV projections: tiled LDS GEMM ----------------
// QKV[row][J], J in [0,384): 0..127 = Q, 128..255 = K, 256..383 = V

#define R_T 32
#define JC_ 48
#define NCHUNK_ 8
#define LDH_ 132

__global__ __launch_bounds__(256) void qkv_kernel(
    const float* __restrict__ h,
    const float* __restrict__ Wq, const float* __restrict__ bq,
    const float* __restrict__ Wk, const float* __restrict__ bk,
    const float* __restrict__ Wv, const float* __restrict__ bv,
    float* __restrict__ QKV)
{
    __shared__ __align__(16) float hs[R_T][LDH_];
    __shared__ __align__(16) float wsm[JC_][LDH_];
    __shared__ float bsm[384];

    int tid = threadIdx.x;
    int row0 = blockIdx.x * R_T;

    for (int f = tid; f < 384; f += 256)
        bsm[f] = (f < 128) ? bq[f] : (f < 256 ? bk[f - 128] : bv[f - 256]);

    for (int f = tid; f < R_T * 32; f += 256) {
        int r = f >> 5, c4 = f & 31;
        *(float4*)(&hs[r][c4 * 4]) = *(const float4*)(h + (long)(row0 + r) * HID_ + c4 * 4);
    }

    int rg = tid & 15;
    int cg = tid >> 4;

    for (int jc = 0; jc < NCHUNK_; ++jc) {
        __syncthreads();
        for (int f = tid; f < JC_ * 32; f += 256) {
            int jr = f >> 5, c4 = f & 31;
            int J = jc * JC_ + jr;
            const float* Wp = (J < 128) ? (Wq + (long)J * HID_)
                            : (J < 256) ? (Wk + (long)(J - 128) * HID_)
                                        : (Wv + (long)(J - 256) * HID_);
            *(float4*)(&wsm[jr][c4 * 4]) = *(const float4*)(Wp + c4 * 4);
        }
        __syncthreads();

        float a00 = 0.f, a01 = 0.f, a02 = 0.f, a10 = 0.f, a11 = 0.f, a12 = 0.f;
        #pragma unroll 8
        for (int k4 = 0; k4 < 32; ++k4) {
            float4 h0 = *(const float4*)(&hs[rg][k4 * 4]);
            float4 h1 = *(const float4*)(&hs[rg + 16][k4 * 4]);
            float4 w0 = *(const float4*)(&wsm[cg][k4 * 4]);
            float4 w1 = *(const float4*)(&wsm[cg + 16][k4 * 4]);
            float4 w2 = *(const float4*)(&wsm[cg + 32][k4 * 4]);
            a00 += h0.x*w0.x + h0.y*w0.y + h0.z*w0.z + h0.w*w0.w;
            a01 += h0.x*w1.x + h0.y*w1.y + h0.z*w1.z + h0.w*w1.w;
            a02 += h0.x*w2.x + h0.y*w2.y + h0.z*w2.z + h0.w*w2.w;
            a10 += h1.x*w0.x + h1.y*w0.y + h1.z*w0.z + h1.w*w0.w;
            a11 += h1.x*w1.x + h1.y*w1.y + h1.z*w1.z + h1.w*w1.w;
            a12 += h1.x*w2.x + h1.y*w2.y + h1.z*w2.z + h1.w*w2.w;
        }

        int J0 = jc * JC_ + cg;
        long r0 = (long)(row0 + rg) * 384;
        long r1 = (long)(row0 + rg + 16) * 384;
        QKV[r0 + J0]      = a00 + bsm[J0];
        QKV[r0 + J0 + 16] = a01 + bsm[J0 + 16];
        QKV[r0 + J0 + 32] = a02 + bsm[J0 + 32];
        QKV[r1 + J0]      = a10 + bsm[J0];
        QKV[r1 + J0 + 16] = a11 + bsm[J0 + 16];
        QKV[r1 + J0 + 32] = a12 + bsm[J0 + 32];
    }
}

// ---------------- DPP 16-lane head reduce (no LDS pipe) ----------------

template <int CTRL>
__device__ __forceinline__ float dpp_add(float x) {
    int y = __builtin_amdgcn_mov_dpp(__float_as_int(x), CTRL, 0xF, 0xF, true);
    return x + __int_as_float(y);
}
__device__ __forceinline__ float hsum16(float p) {
    p = dpp_add<0xB1>(p);   // quad_perm [1,0,3,2]  (xor 1)
    p = dpp_add<0x4E>(p);   // quad_perm [2,3,0,1]  (xor 2)
    p = dpp_add<0x141>(p);  // row_half_mirror      (xor 4)
    p = dpp_add<0x140>(p);  // row_mirror           (xor 8)
    return p;
}

// ---------------- fused per-(b,node): edge loop + softmax-agg + update + LN ----------------
// 256 threads: j = tid&127 (feature), half = tid>>7 (edge-parity split for 2x MLP).

#define MAXDEG 256

__global__ __launch_bounds__(256) void node_kernel(
    const float* __restrict__ h, const float* __restrict__ edge_attr,
    const int* __restrict__ ei,
    const float* __restrict__ QKV,
    const float* __restrict__ We, const float* __restrict__ be,
    const float* __restrict__ attn_vec,
    const float* __restrict__ Ws, const float* __restrict__ bs,
    const float* __restrict__ Wa, const float* __restrict__ ba,
    const float* __restrict__ ln_g, const float* __restrict__ ln_b,
    const int* __restrict__ off, const int* __restrict__ csr,
    float* __restrict__ out)
{
    int n = blockIdx.x;
    int b = blockIdx.y;
    int tid = threadIdx.x;
    int j = tid & 127;
    int half = tid >> 7;

    __shared__ int eL[MAXDEG], sL[MAXDEG];
    __shared__ __align__(16) float hL[HID_];
    __shared__ __align__(16) float aggL[HID_];
    __shared__ float partA[2][HID_], partD[2][HID_], updL[2][HID_];
    __shared__ float red[4];

    float4 we[8];
    const float4* We4 = (const float4*)(We + (long)j * ED_);
    #pragma unroll
    for (int c = 0; c < 8; ++c) we[c] = We4[c];

    float bej = be[j];
    float avj = attn_vec[j];
    long nb = (long)b * N_ + n;
    float qj = QKV[nb * 384 + j];
    if (half == 0) hL[j] = h[nb * HID_ + j];

    int o0 = off[n];
    int deg = off[n + 1] - o0;
    float den = 0.f, acc = 0.f;

    const float* QK = QKV + 128;
    const float* QV = QKV + 256;
    const float* eab = edge_attr + (long)b * E_ * ED_;
    long bN384 = (long)b * N_ * 384;

    for (int base = 0; base < deg; base += MAXDEG) {
        int cnt = min(deg - base, MAXDEG);
        __syncthreads();
        for (int t = tid; t < cnt; t += 256) {
            int e = csr[o0 + base + t];
            eL[t] = e;
            sL[t] = ei[2 * e];
        }
        __syncthreads();

        int i = half;
        for (; i + 2 < cnt; i += 4) {
            int e0 = eL[i],     s0 = sL[i];
            int e1 = eL[i + 2], s1 = sL[i + 2];
            long sb0 = bN384 + (long)s0 * 384;
            long sb1 = bN384 + (long)s1 * 384;
            float k0 = QK[sb0 + j], v0 = QV[sb0 + j];
            float k1 = QK[sb1 + j], v1 = QV[sb1 + j];
            const float4* ea0 = (const float4*)(eab + (long)e0 * ED_);
            const float4* ea1 = (const float4*)(eab + (long)e1 * ED_);
            float ej0 = bej, ej1 = bej;
            #pragma unroll
            for (int c = 0; c < 8; ++c) {
                float4 a0 = ea0[c], a1 = ea1[c];
                ej0 += we[c].x*a0.x + we[c].y*a0.y + we[c].z*a0.z + we[c].w*a0.w;
                ej1 += we[c].x*a1.x + we[c].y*a1.y + we[c].z*a1.z + we[c].w*a1.w;
            }
            float y0 = qj + k0 + ej0;
            float y1 = qj + k1 + ej1;
            float t0 = 1.f - 2.f * __builtin_amdgcn_rcpf(__expf(2.f * y0) + 1.f);
            float t1 = 1.f - 2.f * __builtin_amdgcn_rcpf(__expf(2.f * y1) + 1.f);
            float p0 = hsum16(t0 * avj);
            float p1 = hsum16(t1 * avj);
            float x0 = __expf(p0 * 0.25f);
            float x1 = __expf(p1 * 0.25f);
            den += x0 + x1;
            acc += x0 * (v0 + ej0) + x1 * (v1 + ej1);
        }
        for (; i < cnt; i += 2) {
            int e0 = eL[i], s0 = sL[i];
            long sb0 = bN384 + (long)s0 * 384;
            float k0 = QK[sb0 + j], v0 = QV[sb0 + j];
            const float4* ea0 = (const float4*)(eab + (long)e0 * ED_);
            float ej0 = bej;
            #pragma unroll
            for (int c = 0; c < 8; ++c) {
                float4 a0 = ea0[c];
                ej0 += we[c].x*a0.x + we[c].y*a0.y + we[c].z*a0.z + we[c].w*a0.w;
            }
            float y0 = qj + k0 + ej0;
            float t0 = 1.f - 2.f * __builtin_amdgcn_rcpf(__expf(2.f * y0) + 1.f);
            float p0 = hsum16(t0 * avj);
            float x0 = __expf(p0 * 0.25f);
            den += x0;
            acc += x0 * (v0 + ej0);
        }
    }

    partA[half][j] = acc;
    partD[half][j] = den;
    __syncthreads();

    if (half == 0) {
        float a = partA[0][j] + partA[1][j];
        float d = partD[0][j] + partD[1][j];
        aggL[j] = (deg > 0) ? a * __builtin_amdgcn_rcpf(d) : 0.f;
    }
    __syncthreads();

    // update GEMV split: half0 -> h . Ws[j,:], half1 -> agg . Wa[j,:]
    {
        const float4* w4 = (const float4*)((half == 0 ? Ws : Wa) + (long)j * HID_);
        const float4* x4 = (const float4*)(half == 0 ? hL : aggL);
        float part = 0.f;
        #pragma unroll 8
        for (int k4 = 0; k4 < 32; ++k4) {
            float4 wv = w4[k4], xv = x4[k4];
            part += wv.x*xv.x + wv.y*xv.y + wv.z*xv.z + wv.w*xv.w;
        }
        updL[half][j] = part;
    }
    __syncthreads();

    float x = 0.f;
    if (half == 0) {
        float upd = updL[0][j] + updL[1][j] + bs[j] + ba[j];
        float g = 0.5f * upd * (1.f + erff(upd * 0.70710678118654752f));
        x = hL[j] + g;
        float s = x, s2 = x * x;
        #pragma unroll
        for (int m = 1; m < 64; m <<= 1) { s += __shfl_xor(s, m); s2 += __shfl_xor(s2, m); }
        int wv_ = j >> 6;
        if ((j & 63) == 0) { red[wv_] = s; red[2 + wv_] = s2; }
    }
    __syncthreads();
    if (half == 0) {
        float S = red[0] + red[1], S2 = red[2] + red[3];
        float mu = S * (1.f / 128.f);
        float var = S2 * (1.f / 128.f) - mu * mu;
        float o = (x - mu) * rsqrtf(var + 1e-5f) * ln_g[j] + ln_b[j];
        out[nb * HID_ + j] = o;
    }
}

// ---------------- launch ----------------

extern "C" void kernel_launch(void* const* d_in, const int* in_sizes, int n_in,
                              void* d_out, int out_size, void* d_ws, size_t ws_size,
                              hipStream_t stream) {
    const float* h         = (const float*)d_in[0];
    const float* edge_attr = (const float*)d_in[1];
    const int*   ei        = (const int*)  d_in[2];
    const float* Wq = (const float*)d_in[3];
    const float* bq = (const float*)d_in[4];
    const float* Wk = (const float*)d_in[5];
    const float* bk = (const float*)d_in[6];
    const float* Wv = (const float*)d_in[7];
    const float* bv = (const float*)d_in[8];
    const float* We = (const float*)d_in[9];
    const float* be = (const float*)d_in[10];
    const float* attn_vec = (const float*)d_in[11];
    const float* Ws = (const float*)d_in[12];
    const float* bs = (const float*)d_in[13];
    const float* Wa = (const float*)d_in[14];
    const float* ba = (const float*)d_in[15];
    const float* ln_g = (const float*)d_in[16];
    const float* ln_b = (const float*)d_in[17];
    float* out = (float*)d_out;

    size_t p = 0;
    auto alloc = [&](size_t bytes) { size_t r = p; p += (bytes + 255) & ~(size_t)255; return r; };
    char* ws = (char*)d_ws;
    float* QKV = (float*)(ws + alloc((size_t)ROWS_ * 384 * 4));
    int* deg    = (int*)(ws + alloc((size_t)N_ * 4));
    int* cursor = (int*)(ws + alloc((size_t)N_ * 4));
    int* off    = (int*)(ws + alloc((size_t)(N_ + 1) * 4));
    int* csr    = (int*)(ws + alloc((size_t)E_ * 4));
    (void)ws_size;

    zero_kernel<<<(N_ + 255) / 256, 256, 0, stream>>>(deg, cursor, N_);
    hist_kernel<<<(E_ + 255) / 256, 256, 0, stream>>>(ei, deg, E_);
    scan_kernel<<<1, 256, 0, stream>>>(deg, off, N_);
    fill_kernel<<<(E_ + 255) / 256, 256, 0, stream>>>(ei, off, cursor, csr, E_);

    qkv_kernel<<<ROWS_ / R_T, 256, 0, stream>>>(h, Wq, bq, Wk, bk, Wv, bv, QKV);

    dim3 grid(N_, B_);
    node_kernel<<<grid, 256, 0, stream>>>(h, edge_attr, ei, QKV,
                                          We, be, attn_vec, Ws, bs, Wa, ba,
                                          ln_g, ln_b, off, csr, out);
}

// Round 5
// 296.015 us; speedup vs baseline: 2.1550x; 2.1550x over previous
//
#include <hip/hip_runtime.h>
#include <math.h>

#define B_   2
#define N_   10000
#define E_   160000
#define HID_ 128
#define ED_  32
#define NH_  8
#define HD_  16
#define ROWS_ (B_ * N_)   // 20000

// ---------------- CSR build ----------------

__global__ void zero_kernel(int* __restrict__ deg, int* __restrict__ cursor, int n) {
    int i = blockIdx.x * 256 + threadIdx.x;
    if (i < n) { deg[i] = 0; cursor[i] = 0; }
}

__global__ void hist_kernel(const int* __restrict__ ei, int* __restrict__ deg, int E) {
    int e = blockIdx.x * 256 + threadIdx.x;
    if (e < E) atomicAdd(&deg[ei[2 * e + 1]], 1);
}

__global__ __launch_bounds__(256) void scan_kernel(const int* __restrict__ deg,
                                                   int* __restrict__ off, int N) {
    __shared__ int sums[256];
    int t = threadIdx.x;
    int chunk = (N + 255) / 256;
    int s0 = t * chunk, s1 = min(N, s0 + chunk);
    int s = 0;
    for (int i = s0; i < s1; ++i) s += deg[i];
    sums[t] = s;
    __syncthreads();
    if (t == 0) {
        int run = 0;
        for (int i = 0; i < 256; ++i) { int v = sums[i]; sums[i] = run; run += v; }
        off[N] = run;
    }
    __syncthreads();
    int run = sums[t];
    for (int i = s0; i < s1; ++i) { off[i] = run; run += deg[i]; }
}

__global__ void fill_kernel(const int* __restrict__ ei, const int* __restrict__ off,
                            int* __restrict__ cursor, int* __restrict__ csr, int E) {
    int e = blockIdx.x * 256 + threadIdx.x;
    if (e < E) {
        int d = ei[2 * e + 1];
        int p = atomicAdd(&cursor[d], 1);
        csr[off[d] + p] = e;
    }
}

// ---------------- node QKV projections: tiled LDS GEMM ----------------
// Outputs: Q[row][128], KV[row][256] with KV[row][2j]=K_j, KV[row][2j+1]=V_j.

#define R_T 32
#define JC_ 48
#define NCHUNK_ 8
#define LDH_ 132

__global__ __launch_bounds__(256) void qkv_kernel(
    const float* __restrict__ h,
    const float* __restrict__ Wq, const float* __restrict__ bq,
    const float* __restrict__ Wk, const float* __restrict__ bk,
    const float* __restrict__ Wv, const float* __restrict__ bv,
    float* __restrict__ Q, float* __restrict__ KV)
{
    __shared__ __align__(16) float hs[R_T][LDH_];
    __shared__ __align__(16) float wsm[JC_][LDH_];
    __shared__ float bsm[384];

    int tid = threadIdx.x;
    int row0 = blockIdx.x * R_T;

    for (int f = tid; f < 384; f += 256)
        bsm[f] = (f < 128) ? bq[f] : (f < 256 ? bk[f - 128] : bv[f - 256]);

    for (int f = tid; f < R_T * 32; f += 256) {
        int r = f >> 5, c4 = f & 31;
        *(float4*)(&hs[r][c4 * 4]) = *(const float4*)(h + (long)(row0 + r) * HID_ + c4 * 4);
    }

    int rg = tid & 15;
    int cg = tid >> 4;

    auto store = [&](long row, int J, float a) {
        float v = a + bsm[J];
        if (J < 128)        Q[row * 128 + J] = v;
        else if (J < 256)   KV[row * 256 + 2 * (J - 128)] = v;
        else                KV[row * 256 + 2 * (J - 256) + 1] = v;
    };

    for (int jc = 0; jc < NCHUNK_; ++jc) {
        __syncthreads();
        for (int f = tid; f < JC_ * 32; f += 256) {
            int jr = f >> 5, c4 = f & 31;
            int J = jc * JC_ + jr;
            const float* Wp = (J < 128) ? (Wq + (long)J * HID_)
                            : (J < 256) ? (Wk + (long)(J - 128) * HID_)
                                        : (Wv + (long)(J - 256) * HID_);
            *(float4*)(&wsm[jr][c4 * 4]) = *(const float4*)(Wp + c4 * 4);
        }
        __syncthreads();

        float a00 = 0.f, a01 = 0.f, a02 = 0.f, a10 = 0.f, a11 = 0.f, a12 = 0.f;
        #pragma unroll 8
        for (int k4 = 0; k4 < 32; ++k4) {
            float4 h0 = *(const float4*)(&hs[rg][k4 * 4]);
            float4 h1 = *(const float4*)(&hs[rg + 16][k4 * 4]);
            float4 w0 = *(const float4*)(&wsm[cg][k4 * 4]);
            float4 w1 = *(const float4*)(&wsm[cg + 16][k4 * 4]);
            float4 w2 = *(const float4*)(&wsm[cg + 32][k4 * 4]);
            a00 += h0.x*w0.x + h0.y*w0.y + h0.z*w0.z + h0.w*w0.w;
            a01 += h0.x*w1.x + h0.y*w1.y + h0.z*w1.z + h0.w*w1.w;
            a02 += h0.x*w2.x + h0.y*w2.y + h0.z*w2.z + h0.w*w2.w;
            a10 += h1.x*w0.x + h1.y*w0.y + h1.z*w0.z + h1.w*w0.w;
            a11 += h1.x*w1.x + h1.y*w1.y + h1.z*w1.z + h1.w*w1.w;
            a12 += h1.x*w2.x + h1.y*w2.y + h1.z*w2.z + h1.w*w2.w;
        }

        int J0 = jc * JC_ + cg;
        long r0 = row0 + rg;
        long r1 = row0 + rg + 16;
        store(r0, J0,      a00);
        store(r0, J0 + 16, a01);
        store(r0, J0 + 32, a02);
        store(r1, J0,      a10);
        store(r1, J0 + 16, a11);
        store(r1, J0 + 32, a12);
    }
}

// ---------------- DPP 16-lane head reduce ----------------

template <int CTRL>
__device__ __forceinline__ float dpp_add(float x) {
    int y = __builtin_amdgcn_mov_dpp(__float_as_int(x), CTRL, 0xF, 0xF, true);
    return x + __int_as_float(y);
}
__device__ __forceinline__ float hsum16(float p) {
    p = dpp_add<0xB1>(p);   // quad_perm xor1
    p = dpp_add<0x4E>(p);   // quad_perm xor2
    p = dpp_add<0x141>(p);  // row_half_mirror
    p = dpp_add<0x140>(p);  // row_mirror
    return p;
}

// ---------------- fused node kernel: 4 nodes/block, 128 threads ----------------

#define NPB 4
#define CHUNK 96

__global__ __launch_bounds__(128, 4) void node_kernel(
    const float* __restrict__ h, const float* __restrict__ edge_attr,
    const int* __restrict__ ei,
    const float* __restrict__ Q, const float* __restrict__ KV,
    const float* __restrict__ We, const float* __restrict__ be,
    const float* __restrict__ attn_vec,
    const float* __restrict__ Ws, const float* __restrict__ bs,
    const float* __restrict__ Wa, const float* __restrict__ ba,
    const float* __restrict__ ln_g, const float* __restrict__ ln_b,
    const int* __restrict__ off, const int* __restrict__ csr,
    float* __restrict__ out)
{
    int n0 = blockIdx.x * NPB;
    int b  = blockIdx.y;
    int j  = threadIdx.x;           // 0..127
    long bN = (long)b * N_;

    __shared__ int eL[CHUNK], sL[CHUNK];
    __shared__ __align__(16) float eaL[CHUNK][ED_];
    __shared__ __align__(16) float hL[NPB][HID_];
    __shared__ __align__(16) float aggL[NPB][HID_];
    __shared__ float red[4];

    // We row j in registers
    float4 we[8];
    {
        const float4* We4 = (const float4*)(We + (long)j * ED_);
        #pragma unroll
        for (int c = 0; c < 8; ++c) we[c] = We4[c];
    }
    float bej = be[j];
    float avj = attn_vec[j];

    // per-node q and h
    float q0 = Q[(bN + n0 + 0) * 128 + j];
    float q1 = Q[(bN + n0 + 1) * 128 + j];
    float q2 = Q[(bN + n0 + 2) * 128 + j];
    float q3 = Q[(bN + n0 + 3) * 128 + j];
    hL[0][j] = h[(bN + n0 + 0) * HID_ + j];
    hL[1][j] = h[(bN + n0 + 1) * HID_ + j];
    hL[2][j] = h[(bN + n0 + 2) * HID_ + j];
    hL[3][j] = h[(bN + n0 + 3) * HID_ + j];

    int o0 = off[n0];
    int c1 = off[n0 + 1] - o0, c2 = off[n0 + 2] - o0,
        c3 = off[n0 + 3] - o0, c4_ = off[n0 + 4] - o0;
    int total = c4_;

    const float* eab = edge_attr + (long)b * E_ * ED_;

    float acc0 = 0.f, den0 = 0.f, acc1 = 0.f, den1 = 0.f;
    float acc2 = 0.f, den2 = 0.f, acc3 = 0.f, den3 = 0.f;

    // one edge: k,v gather + E-dot from LDS + tanh + head-sum + exp
    auto edge_body = [&](int i, float qg, float& accg, float& deng) {
        int s = sL[i];
        float2 kv = *(const float2*)(KV + (bN + s) * 256 + 2 * j);
        float ej = bej;
        #pragma unroll
        for (int c = 0; c < 8; ++c) {
            float4 a = *(const float4*)(&eaL[i][c * 4]);
            ej += we[c].x*a.x + we[c].y*a.y + we[c].z*a.z + we[c].w*a.w;
        }
        float y = qg + kv.x + ej;
        float t = 1.f - 2.f * __builtin_amdgcn_rcpf(__expf(2.f * y) + 1.f);
        float p = hsum16(t * avj);
        float ex = __expf(p * 0.25f);
        deng += ex;
        accg += ex * (kv.y + ej);
    };

    auto range_loop = [&](int lo, int hi, float qg, float& accg, float& deng) {
        int i = lo;
        for (; i + 1 < hi; i += 2) {   // unroll 2: two independent gathers in flight
            edge_body(i, qg, accg, deng);
            edge_body(i + 1, qg, accg, deng);
        }
        if (i < hi) edge_body(i, qg, accg, deng);
    };

    for (int tau = 0; tau < total; tau += CHUNK) {
        int rows = min(total - tau, CHUNK);
        __syncthreads();   // LDS reuse safe
        for (int t = j; t < rows; t += 128) {
            int e = csr[o0 + tau + t];
            eL[t] = e;
            sL[t] = ei[2 * e];
        }
        __syncthreads();
        for (int idx = j; idx < rows * 8; idx += 128) {
            int r = idx >> 3, c = idx & 7;
            *(float4*)(&eaL[r][c * 4]) = *(const float4*)(eab + (long)eL[r] * ED_ + c * 4);
        }
        __syncthreads();

        range_loop(max(0 - tau, 0),  min(c1 - tau, rows), q0, acc0, den0);
        range_loop(max(c1 - tau, 0), min(c2 - tau, rows), q1, acc1, den1);
        range_loop(max(c2 - tau, 0), min(c3 - tau, rows), q2, acc2, den2);
        range_loop(max(c3 - tau, 0), min(c4_ - tau, rows), q3, acc3, den3);
    }

    aggL[0][j] = (c1 > 0)   ? acc0 * __builtin_amdgcn_rcpf(den0) : 0.f;
    aggL[1][j] = (c2 > c1)  ? acc1 * __builtin_amdgcn_rcpf(den1) : 0.f;
    aggL[2][j] = (c3 > c2)  ? acc2 * __builtin_amdgcn_rcpf(den2) : 0.f;
    aggL[3][j] = (c4_ > c3) ? acc3 * __builtin_amdgcn_rcpf(den3) : 0.f;
    __syncthreads();

    // update GEMV for 4 nodes with one pass over Ws/Wa rows
    float u0 = 0.f, u1 = 0.f, u2 = 0.f, u3 = 0.f;
    {
        const float4* ws4 = (const float4*)(Ws + (long)j * HID_);
        const float4* wa4 = (const float4*)(Wa + (long)j * HID_);
        #pragma unroll 4
        for (int k4 = 0; k4 < 32; ++k4) {
            float4 w = ws4[k4], a = wa4[k4];
            float4 x0 = *(const float4*)(&hL[0][k4 * 4]);
            float4 x1 = *(const float4*)(&hL[1][k4 * 4]);
            float4 x2 = *(const float4*)(&hL[2][k4 * 4]);
            float4 x3 = *(const float4*)(&hL[3][k4 * 4]);
            float4 g0 = *(const float4*)(&aggL[0][k4 * 4]);
            float4 g1 = *(const float4*)(&aggL[1][k4 * 4]);
            float4 g2 = *(const float4*)(&aggL[2][k4 * 4]);
            float4 g3 = *(const float4*)(&aggL[3][k4 * 4]);
            u0 += w.x*x0.x + w.y*x0.y + w.z*x0.z + w.w*x0.w
                + a.x*g0.x + a.y*g0.y + a.z*g0.z + a.w*g0.w;
            u1 += w.x*x1.x + w.y*x1.y + w.z*x1.z + w.w*x1.w
                + a.x*g1.x + a.y*g1.y + a.z*g1.z + a.w*g1.w;
            u2 += w.x*x2.x + w.y*x2.y + w.z*x2.z + w.w*x2.w
                + a.x*g2.x + a.y*g2.y + a.z*g2.z + a.w*g2.w;
            u3 += w.x*x3.x + w.y*x3.y + w.z*x3.z + w.w*x3.w
                + a.x*g3.x + a.y*g3.y + a.z*g3.z + a.w*g3.w;
        }
    }
    float bias = bs[j] + ba[j];
    float gl = ln_g[j], bl = ln_b[j];

    auto finish = [&](int g, float ug) {
        float upd = ug + bias;
        float ge = 0.5f * upd * (1.f + erff(upd * 0.70710678118654752f));
        float x = hL[g][j] + ge;
        float s = x, s2 = x * x;
        #pragma unroll
        for (int m = 1; m < 64; m <<= 1) { s += __shfl_xor(s, m); s2 += __shfl_xor(s2, m); }
        __syncthreads();   // red[] reuse safe
        int wv = j >> 6;
        if ((j & 63) == 0) { red[wv] = s; red[2 + wv] = s2; }
        __syncthreads();
        float S = red[0] + red[1], S2 = red[2] + red[3];
        float mu = S * (1.f / 128.f);
        float var = S2 * (1.f / 128.f) - mu * mu;
        out[(bN + n0 + g) * HID_ + j] = (x - mu) * rsqrtf(var + 1e-5f) * gl + bl;
    };
    finish(0, u0);
    finish(1, u1);
    finish(2, u2);
    finish(3, u3);
}

// ---------------- launch ----------------

extern "C" void kernel_launch(void* const* d_in, const int* in_sizes, int n_in,
                              void* d_out, int out_size, void* d_ws, size_t ws_size,
                              hipStream_t stream) {
    const float* h         = (const float*)d_in[0];
    const float* edge_attr = (const float*)d_in[1];
    const int*   ei        = (const int*)  d_in[2];
    const float* Wq = (const float*)d_in[3];
    const float* bq = (const float*)d_in[4];
    const float* Wk = (const float*)d_in[5];
    const float* bk = (const float*)d_in[6];
    const float* Wv = (const float*)d_in[7];
    const float* bv = (const float*)d_in[8];
    const float* We = (const float*)d_in[9];
    const float* be = (const float*)d_in[10];
    const float* attn_vec = (const float*)d_in[11];
    const float* Ws = (const float*)d_in[12];
    const float* bs = (const float*)d_in[13];
    const float* Wa = (const float*)d_in[14];
    const float* ba = (const float*)d_in[15];
    const float* ln_g = (const float*)d_in[16];
    const float* ln_b = (const float*)d_in[17];
    float* out = (float*)d_out;

    size_t p = 0;
    auto alloc = [&](size_t bytes) { size_t r = p; p += (bytes + 255) & ~(size_t)255; return r; };
    char* ws = (char*)d_ws;
    float* Q    = (float*)(ws + alloc((size_t)ROWS_ * 128 * 4));
    float* KV   = (float*)(ws + alloc((size_t)ROWS_ * 256 * 4));
    int* deg    = (int*)(ws + alloc((size_t)N_ * 4));
    int* cursor = (int*)(ws + alloc((size_t)N_ * 4));
    int* off    = (int*)(ws + alloc((size_t)(N_ + 1) * 4));
    int* csr    = (int*)(ws + alloc((size_t)E_ * 4));
    (void)ws_size;

    zero_kernel<<<(N_ + 255) / 256, 256, 0, stream>>>(deg, cursor, N_);
    hist_kernel<<<(E_ + 255) / 256, 256, 0, stream>>>(ei, deg, E_);
    scan_kernel<<<1, 256, 0, stream>>>(deg, off, N_);
    fill_kernel<<<(E_ + 255) / 256, 256, 0, stream>>>(ei, off, cursor, csr, E_);

    qkv_kernel<<<ROWS_ / R_T, 256, 0, stream>>>(h, Wq, bq, Wk, bk, Wv, bv, Q, KV);

    dim3 grid(N_ / NPB, B_);
    node_kernel<<<grid, 128, 0, stream>>>(h, edge_attr, ei, Q, KV,
                                          We, be, attn_vec, Ws, bs, Wa, ba,
                                          ln_g, ln_b, off, csr, out);
}

// Round 7
// 206.143 us; speedup vs baseline: 3.0945x; 1.4360x over previous
//
#include <hip/hip_runtime.h>
#include <math.h>
#include <stdint.h>

#define B_   2
#define N_   10000
#define E_   160000
#define HID_ 128
#define ED_  32
#define NH_  8
#define HD_  16
#define ROWS_ (B_ * N_)   // 20000

using half2_t = __attribute__((ext_vector_type(2))) _Float16;

__device__ __forceinline__ half2_t f2h2(float a, float b) {
    return __builtin_bit_cast(half2_t, __builtin_amdgcn_cvt_pkrtz(a, b));
}
__device__ __forceinline__ uint32_t pkh2(float a, float b) {
    return __builtin_bit_cast(uint32_t, __builtin_amdgcn_cvt_pkrtz(a, b));
}

// ---------------- CSR build ----------------

__global__ void zero_kernel(int* __restrict__ deg, int* __restrict__ cursor, int n) {
    int i = blockIdx.x * 256 + threadIdx.x;
    if (i < n) { deg[i] = 0; cursor[i] = 0; }
}

__global__ void hist_kernel(const int* __restrict__ ei, int* __restrict__ deg, int E) {
    int e = blockIdx.x * 256 + threadIdx.x;
    if (e < E) atomicAdd(&deg[ei[2 * e + 1]], 1);
}

__global__ __launch_bounds__(256) void scan_kernel(const int* __restrict__ deg,
                                                   int* __restrict__ off, int N) {
    __shared__ int sums[256];
    int t = threadIdx.x;
    int chunk = (N + 255) / 256;
    int s0 = t * chunk, s1 = min(N, s0 + chunk);
    int s = 0;
    for (int i = s0; i < s1; ++i) s += deg[i];
    sums[t] = s;
    __syncthreads();
    if (t == 0) {
        int run = 0;
        for (int i = 0; i < 256; ++i) { int v = sums[i]; sums[i] = run; run += v; }
        off[N] = run;
    }
    __syncthreads();
    int run = sums[t];
    for (int i = s0; i < s1; ++i) { off[i] = run; run += deg[i]; }
}

__global__ void fill_kernel(const int* __restrict__ ei, const int* __restrict__ off,
                            int* __restrict__ cursor, int* __restrict__ csr, int E) {
    int e = blockIdx.x * 256 + threadIdx.x;
    if (e < E) {
        int d = ei[2 * e + 1];
        int p = atomicAdd(&cursor[d], 1);
        csr[off[d] + p] = e;
    }
}

// ---------------- projections: f16 LDS + v_dot2_f32_f16, 2x4 blocking ----------------
// qkvs: 512 cols = [Q | K | V | S], S = h.Ws^T + bs + ba.

#define R_T 32
#define JC2 64
#define LDH2 68   // dwords (=half2) per row: 64 + 4 pad

__global__ __launch_bounds__(256) void qkvs_kernel(
    const float* __restrict__ h,
    const float* __restrict__ Wq, const float* __restrict__ bq,
    const float* __restrict__ Wk, const float* __restrict__ bk,
    const float* __restrict__ Wv, const float* __restrict__ bv,
    const float* __restrict__ Ws, const float* __restrict__ bs,
    const float* __restrict__ ba,
    float* __restrict__ Q, float* __restrict__ KV, float* __restrict__ S)
{
    __shared__ uint32_t hs[R_T * LDH2];
    __shared__ uint32_t wsm[JC2 * LDH2];
    __shared__ float bsm[512];

    int tid = threadIdx.x;
    int row0 = blockIdx.x * R_T;

    for (int f = tid; f < 512; f += 256) {
        float v;
        if (f < 128) v = bq[f];
        else if (f < 256) v = bk[f - 128];
        else if (f < 384) v = bv[f - 256];
        else v = bs[f - 384] + ba[f - 384];
        bsm[f] = v;
    }

    for (int f = tid; f < R_T * 32; f += 256) {
        int r = f >> 5, c4 = f & 31;
        float4 hv = *(const float4*)(h + (long)(row0 + r) * HID_ + c4 * 4);
        hs[r * LDH2 + c4 * 2]     = pkh2(hv.x, hv.y);
        hs[r * LDH2 + c4 * 2 + 1] = pkh2(hv.z, hv.w);
    }

    int rg = tid & 15;
    int cg = tid >> 4;

    for (int jc = 0; jc < 8; ++jc) {
        __syncthreads();
        for (int f = tid; f < JC2 * 32; f += 256) {
            int jr = f >> 5, c4 = f & 31;
            int J = jc * JC2 + jr;
            const float* Wp;
            if (J < 128)      Wp = Wq + (long)J * HID_;
            else if (J < 256) Wp = Wk + (long)(J - 128) * HID_;
            else if (J < 384) Wp = Wv + (long)(J - 256) * HID_;
            else              Wp = Ws + (long)(J - 384) * HID_;
            float4 wv = *(const float4*)(Wp + c4 * 4);
            wsm[jr * LDH2 + c4 * 2]     = pkh2(wv.x, wv.y);
            wsm[jr * LDH2 + c4 * 2 + 1] = pkh2(wv.z, wv.w);
        }
        __syncthreads();

        float acc[2][4];
        #pragma unroll
        for (int r = 0; r < 2; ++r)
            #pragma unroll
            for (int m = 0; m < 4; ++m) acc[r][m] = 0.f;

        #pragma unroll 4
        for (int kk = 0; kk < 16; ++kk) {
            const half2_t* h0 = (const half2_t*)(hs + rg * LDH2 + kk * 4);
            const half2_t* h1 = (const half2_t*)(hs + (rg + 16) * LDH2 + kk * 4);
            const half2_t* w0 = (const half2_t*)(wsm + cg * LDH2 + kk * 4);
            const half2_t* w1 = (const half2_t*)(wsm + (cg + 16) * LDH2 + kk * 4);
            const half2_t* w2 = (const half2_t*)(wsm + (cg + 32) * LDH2 + kk * 4);
            const half2_t* w3 = (const half2_t*)(wsm + (cg + 48) * LDH2 + kk * 4);
            #pragma unroll
            for (int d = 0; d < 4; ++d) {
                half2_t a0 = h0[d], a1 = h1[d];
                half2_t b0 = w0[d], b1 = w1[d], b2 = w2[d], b3 = w3[d];
                acc[0][0] = __builtin_amdgcn_fdot2(a0, b0, acc[0][0], false);
                acc[0][1] = __builtin_amdgcn_fdot2(a0, b1, acc[0][1], false);
                acc[0][2] = __builtin_amdgcn_fdot2(a0, b2, acc[0][2], false);
                acc[0][3] = __builtin_amdgcn_fdot2(a0, b3, acc[0][3], false);
                acc[1][0] = __builtin_amdgcn_fdot2(a1, b0, acc[1][0], false);
                acc[1][1] = __builtin_amdgcn_fdot2(a1, b1, acc[1][1], false);
                acc[1][2] = __builtin_amdgcn_fdot2(a1, b2, acc[1][2], false);
                acc[1][3] = __builtin_amdgcn_fdot2(a1, b3, acc[1][3], false);
            }
        }

        #pragma unroll
        for (int r = 0; r < 2; ++r) {
            long row = row0 + rg + r * 16;
            #pragma unroll
            for (int m = 0; m < 4; ++m) {
                int J = jc * JC2 + cg + m * 16;
                float v = acc[r][m] + bsm[J];
                if (J < 128)      Q[row * 128 + J] = v;
                else if (J < 256) KV[row * 256 + 2 * (J - 128)] = v;
                else if (J < 384) KV[row * 256 + 2 * (J - 256) + 1] = v;
                else              S[row * 128 + (J - 384)] = v;
            }
        }
    }
}

// wa: A[row][128] = X[row] . Wa^T (no bias; folded into S)
__global__ __launch_bounds__(256) void wa_kernel(
    const float* __restrict__ X, const float* __restrict__ Wa, float* __restrict__ A)
{
    __shared__ uint32_t hs[R_T * LDH2];
    __shared__ uint32_t wsm[JC2 * LDH2];

    int tid = threadIdx.x;
    int row0 = blockIdx.x * R_T;

    for (int f = tid; f < R_T * 32; f += 256) {
        int r = f >> 5, c4 = f & 31;
        float4 hv = *(const float4*)(X + (long)(row0 + r) * HID_ + c4 * 4);
        hs[r * LDH2 + c4 * 2]     = pkh2(hv.x, hv.y);
        hs[r * LDH2 + c4 * 2 + 1] = pkh2(hv.z, hv.w);
    }

    int rg = tid & 15;
    int cg = tid >> 4;

    for (int jc = 0; jc < 2; ++jc) {
        __syncthreads();
        for (int f = tid; f < JC2 * 32; f += 256) {
            int jr = f >> 5, c4 = f & 31;
            int J = jc * JC2 + jr;
            float4 wv = *(const float4*)(Wa + (long)J * HID_ + c4 * 4);
            wsm[jr * LDH2 + c4 * 2]     = pkh2(wv.x, wv.y);
            wsm[jr * LDH2 + c4 * 2 + 1] = pkh2(wv.z, wv.w);
        }
        __syncthreads();

        float acc[2][4];
        #pragma unroll
        for (int r = 0; r < 2; ++r)
            #pragma unroll
            for (int m = 0; m < 4; ++m) acc[r][m] = 0.f;

        #pragma unroll 4
        for (int kk = 0; kk < 16; ++kk) {
            const half2_t* h0 = (const half2_t*)(hs + rg * LDH2 + kk * 4);
            const half2_t* h1 = (const half2_t*)(hs + (rg + 16) * LDH2 + kk * 4);
            const half2_t* w0 = (const half2_t*)(wsm + cg * LDH2 + kk * 4);
            const half2_t* w1 = (const half2_t*)(wsm + (cg + 16) * LDH2 + kk * 4);
            const half2_t* w2 = (const half2_t*)(wsm + (cg + 32) * LDH2 + kk * 4);
            const half2_t* w3 = (const half2_t*)(wsm + (cg + 48) * LDH2 + kk * 4);
            #pragma unroll
            for (int d = 0; d < 4; ++d) {
                half2_t a0 = h0[d], a1 = h1[d];
                half2_t b0 = w0[d], b1 = w1[d], b2 = w2[d], b3 = w3[d];
                acc[0][0] = __builtin_amdgcn_fdot2(a0, b0, acc[0][0], false);
                acc[0][1] = __builtin_amdgcn_fdot2(a0, b1, acc[0][1], false);
                acc[0][2] = __builtin_amdgcn_fdot2(a0, b2, acc[0][2], false);
                acc[0][3] = __builtin_amdgcn_fdot2(a0, b3, acc[0][3], false);
                acc[1][0] = __builtin_amdgcn_fdot2(a1, b0, acc[1][0], false);
                acc[1][1] = __builtin_amdgcn_fdot2(a1, b1, acc[1][1], false);
                acc[1][2] = __builtin_amdgcn_fdot2(a1, b2, acc[1][2], false);
                acc[1][3] = __builtin_amdgcn_fdot2(a1, b3, acc[1][3], false);
            }
        }

        #pragma unroll
        for (int r = 0; r < 2; ++r) {
            long row = row0 + rg + r * 16;
            #pragma unroll
            for (int m = 0; m < 4; ++m) {
                int J = jc * JC2 + cg + m * 16;
                A[row * 128 + J] = acc[r][m];
            }
        }
    }
}

// ---------------- DPP 16-lane head reduce ----------------

template <int CTRL>
__device__ __forceinline__ float dpp_add(float x) {
    int y = __builtin_amdgcn_mov_dpp(__float_as_int(x), CTRL, 0xF, 0xF, true);
    return x + __int_as_float(y);
}
__device__ __forceinline__ float hsum16(float p) {
    p = dpp_add<0xB1>(p);   // quad_perm xor1
    p = dpp_add<0x4E>(p);   // quad_perm xor2
    p = dpp_add<0x141>(p);  // row_half_mirror
    p = dpp_add<0x140>(p);  // row_mirror
    return p;
}

// ---------------- edge aggregation: 4 nodes/block, 128 threads, writes agg ----------------

#define NPB 4
#define CHUNK 96
#define EAS 20   // dwords per staged ea row (16 data + 4 pad)

__global__ __launch_bounds__(128) void node_kernel(
    const float* __restrict__ edge_attr, const int* __restrict__ ei,
    const float* __restrict__ Q, const float* __restrict__ KV,
    const float* __restrict__ We, const float* __restrict__ be,
    const float* __restrict__ attn_vec,
    const int* __restrict__ off, const int* __restrict__ csr,
    float* __restrict__ agg)
{
    int n0 = blockIdx.x * NPB;
    int b  = blockIdx.y;
    int j  = threadIdx.x;           // 0..127
    long bN = (long)b * N_;

    __shared__ int sL[CHUNK];
    __shared__ uint32_t eaL[CHUNK * EAS];

    // We row j in f16 registers (16 half2)
    half2_t we16[16];
    {
        const float4* We4 = (const float4*)(We + (long)j * ED_);
        #pragma unroll
        for (int c = 0; c < 8; ++c) {
            float4 w = We4[c];
            we16[2 * c]     = f2h2(w.x, w.y);
            we16[2 * c + 1] = f2h2(w.z, w.w);
        }
    }
    float bej = be[j];
    float avj = attn_vec[j];

    float q0 = Q[(bN + n0 + 0) * 128 + j];
    float q1 = Q[(bN + n0 + 1) * 128 + j];
    float q2 = Q[(bN + n0 + 2) * 128 + j];
    float q3 = Q[(bN + n0 + 3) * 128 + j];

    int o0 = off[n0];
    int c1 = off[n0 + 1] - o0, c2 = off[n0 + 2] - o0,
        c3 = off[n0 + 3] - o0, c4_ = off[n0 + 4] - o0;
    int total = c4_;

    const float* eab = edge_attr + (long)b * E_ * ED_;
    const float* KVb = KV + bN * 256;

    float acc0 = 0.f, den0 = 0.f, acc1 = 0.f, den1 = 0.f;
    float acc2 = 0.f, den2 = 0.f, acc3 = 0.f, den3 = 0.f;

    auto edge_body = [&](int i, float qg, float& accg, float& deng) {
        int s = sL[i];
        float2 kv = *(const float2*)(KVb + (long)s * 256 + 2 * j);
        float ej = bej;
        const half2_t* ea = (const half2_t*)(eaL + i * EAS);
        #pragma unroll
        for (int c = 0; c < 16; ++c)
            ej = __builtin_amdgcn_fdot2(we16[c], ea[c], ej, false);
        float y = qg + kv.x + ej;
        float t = 1.f - 2.f * __builtin_amdgcn_rcpf(__expf(2.f * y) + 1.f);
        float p = hsum16(t * avj);
        float ex = __expf(p * 0.25f);
        deng += ex;
        accg += ex * (kv.y + ej);
    };

    auto range_loop = [&](int lo, int hi, float qg, float& accg, float& deng) {
        int i = lo;
        for (; i + 3 < hi; i += 4) {   // 4 independent KV gathers in flight
            edge_body(i, qg, accg, deng);
            edge_body(i + 1, qg, accg, deng);
            edge_body(i + 2, qg, accg, deng);
            edge_body(i + 3, qg, accg, deng);
        }
        for (; i < hi; ++i) edge_body(i, qg, accg, deng);
    };

    for (int tau = 0; tau < total; tau += CHUNK) {
        int rows = min(total - tau, CHUNK);
        __syncthreads();   // LDS reuse safe
        for (int t = j; t < rows; t += 128) {
            int e = csr[o0 + tau + t];
            sL[t] = ei[2 * e];
        }
        for (int idx = j; idx < rows * 8; idx += 128) {
            int r = idx >> 3, c = idx & 7;
            int e = csr[o0 + tau + r];   // L1-hot re-read
            float4 f = *(const float4*)(eab + (long)e * ED_ + c * 4);
            eaL[r * EAS + c * 2]     = pkh2(f.x, f.y);
            eaL[r * EAS + c * 2 + 1] = pkh2(f.z, f.w);
        }
        __syncthreads();

        range_loop(max(0 - tau, 0),   min(c1 - tau, rows), q0, acc0, den0);
        range_loop(max(c1 - tau, 0),  min(c2 - tau, rows), q1, acc1, den1);
        range_loop(max(c2 - tau, 0),  min(c3 - tau, rows), q2, acc2, den2);
        range_loop(max(c3 - tau, 0),  min(c4_ - tau, rows), q3, acc3, den3);
    }

    agg[(bN + n0 + 0) * 128 + j] = (c1 > 0)   ? acc0 * __builtin_amdgcn_rcpf(den0) : 0.f;
    agg[(bN + n0 + 1) * 128 + j] = (c2 > c1)  ? acc1 * __builtin_amdgcn_rcpf(den1) : 0.f;
    agg[(bN + n0 + 2) * 128 + j] = (c3 > c2)  ? acc2 * __builtin_amdgcn_rcpf(den2) : 0.f;
    agg[(bN + n0 + 3) * 128 + j] = (c4_ > c3) ? acc3 * __builtin_amdgcn_rcpf(den3) : 0.f;
}

// ---------------- final: x = h + gelu(S + A); LayerNorm ----------------

__global__ __launch_bounds__(128) void final_kernel(
    const float* __restrict__ h, const float* __restrict__ S, const float* __restrict__ A,
    const float* __restrict__ ln_g, const float* __restrict__ ln_b,
    float* __restrict__ out)
{
    long row = blockIdx.x;
    int j = threadIdx.x;
    __shared__ float red[4];

    float upd = S[row * 128 + j] + A[row * 128 + j];
    float ge = 0.5f * upd * (1.f + erff(upd * 0.70710678118654752f));
    float x = h[row * 128 + j] + ge;

    float s = x, s2 = x * x;
    #pragma unroll
    for (int m = 1; m < 64; m <<= 1) { s += __shfl_xor(s, m); s2 += __shfl_xor(s2, m); }
    int wv = j >> 6;
    if ((j & 63) == 0) { red[wv] = s; red[2 + wv] = s2; }
    __syncthreads();
    float Sm = red[0] + red[1], S2m = red[2] + red[3];
    float mu = Sm * (1.f / 128.f);
    float var = S2m * (1.f / 128.f) - mu * mu;
    out[row * 128 + j] = (x - mu) * rsqrtf(var + 1e-5f) * ln_g[j] + ln_b[j];
}

// ---------------- launch ----------------

extern "C" void kernel_launch(void* const* d_in, const int* in_sizes, int n_in,
                              void* d_out, int out_size, void* d_ws, size_t ws_size,
                              hipStream_t stream) {
    const float* h         = (const float*)d_in[0];
    const float* edge_attr = (const float*)d_in[1];
    const int*   ei        = (const int*)  d_in[2];
    const float* Wq = (const float*)d_in[3];
    const float* bq = (const float*)d_in[4];
    const float* Wk = (const float*)d_in[5];
    const float* bk = (const float*)d_in[6];
    const float* Wv = (const float*)d_in[7];
    const float* bv = (const float*)d_in[8];
    const float* We = (const float*)d_in[9];
    const float* be = (const float*)d_in[10];
    const float* attn_vec = (const float*)d_in[11];
    const float* Ws = (const float*)d_in[12];
    const float* bs = (const float*)d_in[13];
    const float* Wa = (const float*)d_in[14];
    const float* ba = (const float*)d_in[15];
    const float* ln_g = (const float*)d_in[16];
    const float* ln_b = (const float*)d_in[17];
    float* out = (float*)d_out;

    size_t p = 0;
    auto alloc = [&](size_t bytes) { size_t r = p; p += (bytes + 255) & ~(size_t)255; return r; };
    char* ws = (char*)d_ws;
    float* Q    = (float*)(ws + alloc((size_t)ROWS_ * 128 * 4));   // reused as A after node_kernel
    float* KV   = (float*)(ws + alloc((size_t)ROWS_ * 256 * 4));
    float* S    = (float*)(ws + alloc((size_t)ROWS_ * 128 * 4));
    float* agg  = (float*)(ws + alloc((size_t)ROWS_ * 128 * 4));
    int* deg    = (int*)(ws + alloc((size_t)N_ * 4));
    int* cursor = (int*)(ws + alloc((size_t)N_ * 4));
    int* off    = (int*)(ws + alloc((size_t)(N_ + 1) * 4));
    int* csr    = (int*)(ws + alloc((size_t)E_ * 4));
    float* A = Q;   // alias: Q dead after node_kernel
    (void)ws_size;

    zero_kernel<<<(N_ + 255) / 256, 256, 0, stream>>>(deg, cursor, N_);
    hist_kernel<<<(E_ + 255) / 256, 256, 0, stream>>>(ei, deg, E_);
    scan_kernel<<<1, 256, 0, stream>>>(deg, off, N_);
    fill_kernel<<<(E_ + 255) / 256, 256, 0, stream>>>(ei, off, cursor, csr, E_);

    qkvs_kernel<<<ROWS_ / R_T, 256, 0, stream>>>(h, Wq, bq, Wk, bk, Wv, bv, Ws, bs, ba,
                                                 Q, KV, S);

    dim3 grid(N_ / NPB, B_);
    node_kernel<<<grid, 128, 0, stream>>>(edge_attr, ei, Q, KV, We, be, attn_vec,
                                          off, csr, agg);

    wa_kernel<<<ROWS_ / R_T, 256, 0, stream>>>(agg, Wa, A);

    final_kernel<<<ROWS_, 128, 0, stream>>>(h, S, A, ln_g, ln_b, out);
}